// Round 9
// baseline (607.405 us; speedup 1.0000x reference)
//
#include <hip/hip_runtime.h>
#include <cstdint>

// ---------------------------------------------------------------------------
// LaSSMDecoder on MI355X — Round 9:
//  (a) KNN query-tiled: 4 queries/block share each loaded point (4x less L2
//      traffic + amortized per-iter overhead); 512 blocks, 4 wave-uniform
//      top-8 lists in named registers per wave.
//  (b) fp32->(hi,lo) bf16 split fused into producers (ln/kwmix/gaterms/
//      ln_unsort/gemm-epilogue) — removes 7 cvt dispatches.
// GEMMs: MFMA 2-term bf16 split (3 products, fp32 accumulate), round 8.
// ---------------------------------------------------------------------------

typedef __attribute__((ext_vector_type(8))) short bf16x8;
typedef __attribute__((ext_vector_type(4))) float f32x4;

__device__ __forceinline__ unsigned short f2bf(float f) {
  unsigned int u = __float_as_uint(f);
  u += 0x7fff + ((u >> 16) & 1);        // RNE
  return (unsigned short)(u >> 16);
}
__device__ __forceinline__ float bf2f(unsigned short h) {
  return __uint_as_float(((unsigned int)h) << 16);
}

// -------------------------- fp32 -> (hi, lo) bf16 planes -------------------
__global__ __launch_bounds__(256) void cvt_kernel(
    const float* __restrict__ src, unsigned short* __restrict__ hi,
    unsigned short* __restrict__ lo, int n4)
{
  const int i = blockIdx.x*256 + threadIdx.x;
  if (i < n4) {
    const float4 v = ((const float4*)src)[i];
    const unsigned short h0=f2bf(v.x), h1=f2bf(v.y), h2=f2bf(v.z), h3=f2bf(v.w);
    const unsigned short l0=f2bf(v.x-bf2f(h0)), l1=f2bf(v.y-bf2f(h1)),
                         l2=f2bf(v.z-bf2f(h2)), l3=f2bf(v.w-bf2f(h3));
    ((uint2*)hi)[i] = make_uint2((unsigned)h0 | ((unsigned)h1<<16),
                                 (unsigned)h2 | ((unsigned)h3<<16));
    ((uint2*)lo)[i] = make_uint2((unsigned)l0 | ((unsigned)l1<<16),
                                 (unsigned)l2 | ((unsigned)l3<<16));
  }
}

// ---------------- per-query wave-uniform top-8 list (named registers) ------
#define KNN_DECL(i)                                                            \
  unsigned int k0_##i=0xFFFFFFFFu,k1_##i=0xFFFFFFFFu,k2_##i=0xFFFFFFFFu,       \
               k3_##i=0xFFFFFFFFu,k4_##i=0xFFFFFFFFu,k5_##i=0xFFFFFFFFu,       \
               k6_##i=0xFFFFFFFFu,k7_##i=0xFFFFFFFFu;                          \
  int id0_##i=0x7fffffff,id1_##i=0x7fffffff,id2_##i=0x7fffffff,                \
      id3_##i=0x7fffffff,id4_##i=0x7fffffff,id5_##i=0x7fffffff,                \
      id6_##i=0x7fffffff,id7_##i=0x7fffffff

// strict-key insert (arrival order ascending -> ties keep earlier index)
#define KNN_INS_Q(i, ukv, uiv)                                                 \
  do {                                                                         \
    const unsigned int _k = (ukv); const int _v = (uiv);                       \
    const bool a0 = _k < k0_##i;                                               \
    const bool a1 = _k < k1_##i;                                               \
    const bool a2 = _k < k2_##i;                                               \
    const bool a3 = _k < k3_##i;                                               \
    const bool a4 = _k < k4_##i;                                               \
    const bool a5 = _k < k5_##i;                                               \
    const bool a6 = _k < k6_##i;                                               \
    k7_##i = a6 ? k6_##i : _k;                  id7_##i = a6 ? id6_##i : _v;   \
    k6_##i = a5 ? k5_##i : (a6 ? _k : k6_##i);  id6_##i = a5 ? id5_##i : (a6 ? _v : id6_##i); \
    k5_##i = a4 ? k4_##i : (a5 ? _k : k5_##i);  id5_##i = a4 ? id4_##i : (a5 ? _v : id5_##i); \
    k4_##i = a3 ? k3_##i : (a4 ? _k : k4_##i);  id4_##i = a3 ? id3_##i : (a4 ? _v : id4_##i); \
    k3_##i = a2 ? k2_##i : (a3 ? _k : k3_##i);  id3_##i = a2 ? id2_##i : (a3 ? _v : id3_##i); \
    k2_##i = a1 ? k1_##i : (a2 ? _k : k2_##i);  id2_##i = a1 ? id1_##i : (a2 ? _v : id2_##i); \
    k1_##i = a0 ? k0_##i : (a1 ? _k : k1_##i);  id1_##i = a0 ? id0_##i : (a1 ? _v : id1_##i); \
    k0_##i = a0 ? _k : k0_##i;                  id0_##i = a0 ? _v : id0_##i;   \
  } while (0)

__device__ __forceinline__ bool ulex_less(unsigned int k, int i,
                                          unsigned int kr, int ir) {
  return k < kr || (k == kr && i < ir);
}

// lexicographic insert (cross-wave merge); caller pre-qualifies vs slot 7
#define KNN_INS_LEXQ(i, ukv, uiv)                                              \
  do {                                                                         \
    const unsigned int _k = (ukv); const int _v = (uiv);                       \
    const bool a0 = ulex_less(_k, _v, k0_##i, id0_##i);                        \
    const bool a1 = ulex_less(_k, _v, k1_##i, id1_##i);                        \
    const bool a2 = ulex_less(_k, _v, k2_##i, id2_##i);                        \
    const bool a3 = ulex_less(_k, _v, k3_##i, id3_##i);                        \
    const bool a4 = ulex_less(_k, _v, k4_##i, id4_##i);                        \
    const bool a5 = ulex_less(_k, _v, k5_##i, id5_##i);                        \
    const bool a6 = ulex_less(_k, _v, k6_##i, id6_##i);                        \
    k7_##i = a6 ? k6_##i : _k;                  id7_##i = a6 ? id6_##i : _v;   \
    k6_##i = a5 ? k5_##i : (a6 ? _k : k6_##i);  id6_##i = a5 ? id5_##i : (a6 ? _v : id6_##i); \
    k5_##i = a4 ? k4_##i : (a5 ? _k : k5_##i);  id5_##i = a4 ? id4_##i : (a5 ? _v : id5_##i); \
    k4_##i = a3 ? k3_##i : (a4 ? _k : k4_##i);  id4_##i = a3 ? id3_##i : (a4 ? _v : id4_##i); \
    k3_##i = a2 ? k2_##i : (a3 ? _k : k3_##i);  id3_##i = a2 ? id2_##i : (a3 ? _v : id3_##i); \
    k2_##i = a1 ? k1_##i : (a2 ? _k : k2_##i);  id2_##i = a1 ? id1_##i : (a2 ? _v : id2_##i); \
    k1_##i = a0 ? k0_##i : (a1 ? _k : k1_##i);  id1_##i = a0 ? id0_##i : (a1 ? _v : id1_##i); \
    k0_##i = a0 ? _k : k0_##i;                  id0_##i = a0 ? _v : id0_##i;   \
  } while (0)

// one distance + ballot + serial-insert round for query i
#define KNN_ROUND(i)                                                           \
  do {                                                                         \
    const float d2 = (qq##i + p.w)                                             \
                   - 2.0f*(qx##i*p.x + qy##i*p.y + qz##i*p.z);                 \
    unsigned int u = __float_as_uint(d2);                                      \
    u ^= (unsigned int)((int)u >> 31) | 0x80000000u;                           \
    unsigned long long m = __ballot(u < k7_##i);                               \
    while (m) {                                                                \
      const int l = __ffsll(m) - 1;                                            \
      m &= m - 1;                                                              \
      const unsigned int uk = (unsigned int)__shfl((int)u, l);                 \
      if (uk < k7_##i) KNN_INS_Q(i, uk, nb + l);                               \
    }                                                                          \
  } while (0)

#define KNN_STORE(i)                                                           \
  do {                                                                         \
    const int o = (i)*32 + wave*8;                                             \
    skey[o+0]=k0_##i; skey[o+1]=k1_##i; skey[o+2]=k2_##i; skey[o+3]=k3_##i;    \
    skey[o+4]=k4_##i; skey[o+5]=k5_##i; skey[o+6]=k6_##i; skey[o+7]=k7_##i;    \
    sidx[o+0]=id0_##i; sidx[o+1]=id1_##i; sidx[o+2]=id2_##i; sidx[o+3]=id3_##i;\
    sidx[o+4]=id4_##i; sidx[o+5]=id5_##i; sidx[o+6]=id6_##i; sidx[o+7]=id7_##i;\
  } while (0)

// -------------------------- prep: pack (sx,sy,sz,|s|^2) as float4 ----------
__global__ void prep_kernel(const float* __restrict__ spos,
                            float4* __restrict__ P4)
{
#pragma clang fp contract(off)
  const int n = blockIdx.x*256 + threadIdx.x;
  if (n < 32768) {
    const float sx = spos[n*3+0], sy = spos[n*3+1], sz = spos[n*3+2];
    P4[n] = make_float4(sx, sy, sz, sx*sx + sy*sy + sz*sz);
  }
}

// -------------------------- KNN: 4 queries / block, 512 blocks -------------
__global__ __launch_bounds__(256) void knn_kernel(
    const float* __restrict__ qpos, const float4* __restrict__ P4,
    int* __restrict__ idx_out)
{
#pragma clang fp contract(off)
  __shared__ unsigned int skey[128];   // [4 queries][4 waves][8 slots]
  __shared__ int          sidx[128];
  const int q0 = blockIdx.x << 2, tid = threadIdx.x;
  const int wave = tid >> 6, lane = tid & 63;
  // query constants (wave-uniform)
  const float qx0 = qpos[(q0+0)*3+0], qy0 = qpos[(q0+0)*3+1], qz0 = qpos[(q0+0)*3+2];
  const float qx1 = qpos[(q0+1)*3+0], qy1 = qpos[(q0+1)*3+1], qz1 = qpos[(q0+1)*3+2];
  const float qx2 = qpos[(q0+2)*3+0], qy2 = qpos[(q0+2)*3+1], qz2 = qpos[(q0+2)*3+2];
  const float qx3 = qpos[(q0+3)*3+0], qy3 = qpos[(q0+3)*3+1], qz3 = qpos[(q0+3)*3+2];
  const float qq0 = qx0*qx0 + qy0*qy0 + qz0*qz0;
  const float qq1 = qx1*qx1 + qy1*qy1 + qz1*qz1;
  const float qq2 = qx2*qx2 + qy2*qy2 + qz2*qz2;
  const float qq3 = qx3*qx3 + qy3*qy3 + qz3*qz3;
  KNN_DECL(0); KNN_DECL(1); KNN_DECL(2); KNN_DECL(3);
  const int base = wave << 13;              // 8192 points per wave
  float4 p = P4[base + lane];
  float4 pn = p;
  for (int it = 0; it < 128; ++it) {
    if (it < 127) pn = P4[base + ((it+1) << 6) + lane];   // prefetch
    const int nb = base + (it << 6);
    KNN_ROUND(0); KNN_ROUND(1); KNN_ROUND(2); KNN_ROUND(3);
    p = pn;
  }
  if (lane == 0) { KNN_STORE(0); KNN_STORE(1); KNN_STORE(2); KNN_STORE(3); }
  __syncthreads();
  if (tid < 4) {
    KNN_DECL(m);
    const int o = tid*32;
    for (int s = 0; s < 32; ++s) {
      const unsigned int uk = skey[o + s];
      const int          ui = sidx[o + s];
      if (ulex_less(uk, ui, k7_m, id7_m)) KNN_INS_LEXQ(m, uk, ui);
    }
    const int ob = (q0 + tid)*8;
    idx_out[ob+0]=id0_m; idx_out[ob+1]=id1_m; idx_out[ob+2]=id2_m; idx_out[ob+3]=id3_m;
    idx_out[ob+4]=id4_m; idx_out[ob+5]=id5_m; idx_out[ob+6]=id6_m; idx_out[ob+7]=id7_m;
  }
}

// -------------------------- inverse permutation ----------------------------
__global__ void inv_kernel(const int* __restrict__ order, int* __restrict__ inv)
{
  int i = blockIdx.x*blockDim.x + threadIdx.x;
  if (i < 4096) { int b = i >> 11, t = i & 2047; inv[(b<<11) + order[i]] = t; }
}

// -------------------------- MFMA GEMM on pre-split bf16 planes -------------
// Y = act(A[rowmap] @ Wt^T + b); optional (Yh,Yl) plane output instead of Y.
#define GBM 128
#define GBN 64
#define GBK 32
#define GLDK 40   // padded LDS row length (bf16 units): 32 + 8
__global__ __launch_bounds__(256) void gemm_mfma(
    const unsigned short* __restrict__ Ahp, const unsigned short* __restrict__ Alp,
    const int* __restrict__ rowmap,
    const unsigned short* __restrict__ Bhp, const unsigned short* __restrict__ Blp,
    const float* __restrict__ bias,
    float* __restrict__ Y,
    unsigned short* __restrict__ Yh, unsigned short* __restrict__ Yl,
    int M, int Nn, int Kd, int act)
{
  __shared__ unsigned short Ah[GBM*GLDK], Al[GBM*GLDK];
  __shared__ unsigned short Bh[GBN*GLDK], Bl[GBN*GLDK];
  const int tid = threadIdx.x;
  const int bm = blockIdx.x, bn = blockIdx.y;
  const int wid = tid >> 6, lane = tid & 63;
  const int wr = wid >> 1, wc = wid & 1;          // 2x2 wave grid
  const int l15 = lane & 15, lk = (lane >> 4) << 3;

  const int sar = tid >> 1, sak = (tid & 1) << 4;
  const int agrow = bm*GBM + sar;
  const int asrc = rowmap ? rowmap[agrow] : agrow;
  const unsigned short* ArH = Ahp + (size_t)asrc * Kd + sak;
  const unsigned short* ArL = Alp + (size_t)asrc * Kd + sak;
  const int sbr = tid >> 2, sbk = (tid & 3) << 3;
  const int wrow = bn*GBN + sbr;
  const bool bok = (wrow < Nn);
  const unsigned short* BrH = Bhp + (size_t)(bok ? wrow : 0) * Kd + sbk;
  const unsigned short* BrL = Blp + (size_t)(bok ? wrow : 0) * Kd + sbk;

  f32x4 acc[4][2];
#pragma unroll
  for (int m = 0; m < 4; ++m)
#pragma unroll
    for (int n = 0; n < 2; ++n) acc[m][n] = (f32x4){0.f,0.f,0.f,0.f};

  const uint4 z4 = make_uint4(0u,0u,0u,0u);
  for (int k0 = 0; k0 < Kd; k0 += GBK) {
    const int ao = sar*GLDK + sak;
    *(uint4*)&Ah[ao]     = *(const uint4*)(ArH + k0);
    *(uint4*)&Ah[ao + 8] = *(const uint4*)(ArH + k0 + 8);
    *(uint4*)&Al[ao]     = *(const uint4*)(ArL + k0);
    *(uint4*)&Al[ao + 8] = *(const uint4*)(ArL + k0 + 8);
    const int bo = sbr*GLDK + sbk;
    *(uint4*)&Bh[bo] = bok ? *(const uint4*)(BrH + k0) : z4;
    *(uint4*)&Bl[bo] = bok ? *(const uint4*)(BrL + k0) : z4;
    __syncthreads();
    bf16x8 afh[4], afl[4], bfh[2], bfl[2];
#pragma unroll
    for (int m = 0; m < 4; ++m) {
      const int row = wr*64 + m*16 + l15;
      afh[m] = *(const bf16x8*)&Ah[row*GLDK + lk];
      afl[m] = *(const bf16x8*)&Al[row*GLDK + lk];
    }
#pragma unroll
    for (int n = 0; n < 2; ++n) {
      const int row = wc*32 + n*16 + l15;
      bfh[n] = *(const bf16x8*)&Bh[row*GLDK + lk];
      bfl[n] = *(const bf16x8*)&Bl[row*GLDK + lk];
    }
#pragma unroll
    for (int m = 0; m < 4; ++m)
#pragma unroll
      for (int n = 0; n < 2; ++n) {
        acc[m][n] = __builtin_amdgcn_mfma_f32_16x16x32_bf16(afh[m], bfh[n], acc[m][n], 0,0,0);
        acc[m][n] = __builtin_amdgcn_mfma_f32_16x16x32_bf16(afh[m], bfl[n], acc[m][n], 0,0,0);
        acc[m][n] = __builtin_amdgcn_mfma_f32_16x16x32_bf16(afl[m], bfh[n], acc[m][n], 0,0,0);
      }
    __syncthreads();
  }
  const int crow0 = bm*GBM + wr*64 + (lane >> 4)*4;
#pragma unroll
  for (int m = 0; m < 4; ++m) {
#pragma unroll
    for (int n = 0; n < 2; ++n) {
      const int col = bn*GBN + wc*32 + n*16 + l15;
      if (col < Nn) {
#pragma unroll
        for (int r = 0; r < 4; ++r) {
          float v = acc[m][n][r];
          if (bias) v += bias[col];
          if (act == 1) v = 0.5f*v*(1.f + erff(v*0.7071067811865475f));
          const size_t idx = (size_t)(crow0 + m*16 + r)*Nn + col;
          if (Yh) {
            const unsigned short h = f2bf(v);
            Yh[idx] = h; Yl[idx] = f2bf(v - bf2f(h));
          } else {
            Y[idx] = v;
          }
        }
      }
    }
  }
}

// -------------------------- kw softmax + neighbor mixing → WB planes -------
__global__ __launch_bounds__(256) void kwmix_kernel(
    const float* __restrict__ QP, const float* __restrict__ wk,
    const float* __restrict__ wb, const float* __restrict__ V,
    unsigned short* __restrict__ Wh, unsigned short* __restrict__ Wl)
{
  const int wave = threadIdx.x >> 6, lane = threadIdx.x & 63;
  const int q = blockIdx.x*4 + wave;
  float qv[4];
#pragma unroll
  for (int j = 0; j < 4; ++j) qv[j] = QP[(size_t)q*256 + lane + 64*j];
  float logit[8];
#pragma unroll
  for (int k = 0; k < 8; ++k) {
    float p = 0.f;
#pragma unroll
    for (int j = 0; j < 4; ++j) p += qv[j]*wk[k*256 + lane + 64*j];
    for (int off = 32; off; off >>= 1) p += __shfl_xor(p, off);
    logit[k] = p + wb[k];
  }
  float mx = logit[0];
#pragma unroll
  for (int k = 1; k < 8; ++k) mx = fmaxf(mx, logit[k]);
  float e[8]; float s = 0.f;
#pragma unroll
  for (int k = 0; k < 8; ++k) { e[k] = expf(logit[k]-mx); s += e[k]; }
  float inv = 1.f/s;
  float acc[4] = {0.f,0.f,0.f,0.f};
#pragma unroll
  for (int k = 0; k < 8; ++k) {
    float kwv = e[k]*inv;
#pragma unroll
    for (int j = 0; j < 4; ++j)
      acc[j] = fmaf(kwv, V[(size_t)(q*8+k)*256 + lane + 64*j], acc[j]);
  }
#pragma unroll
  for (int j = 0; j < 4; ++j) {
    const float v = qv[j]*acc[j];
    const unsigned short h = f2bf(v);
    const size_t o = (size_t)q*256 + lane + 64*j;
    Wh[o] = h; Wl[o] = f2bf(v - bf2f(h));
  }
}

// -------------------------- LayerNorm (fp32 out and/or bf16 planes) --------
__global__ __launch_bounds__(256) void ln_kernel(
    const float* __restrict__ a, const float* __restrict__ b,
    float* __restrict__ out,
    unsigned short* __restrict__ oh, unsigned short* __restrict__ ol,
    int rows)
{
  const int wave = threadIdx.x >> 6, lane = threadIdx.x & 63;
  const int row = blockIdx.x*4 + wave;
  if (row >= rows) return;
  float v[4];
#pragma unroll
  for (int j = 0; j < 4; ++j) {
    float x = a[(size_t)row*256 + lane + 64*j];
    if (b) x += b[(size_t)row*256 + lane + 64*j];
    v[j] = x;
  }
  float s = v[0]+v[1]+v[2]+v[3];
  for (int off = 32; off; off >>= 1) s += __shfl_xor(s, off);
  float m = s * (1.0f/256.0f);
  float t = 0.f;
#pragma unroll
  for (int j = 0; j < 4; ++j) { float d = v[j]-m; t += d*d; }
  for (int off = 32; off; off >>= 1) t += __shfl_xor(t, off);
  float r = rsqrtf(t * (1.0f/256.0f) + 1e-5f);
#pragma unroll
  for (int j = 0; j < 4; ++j) {
    const float y = (v[j]-m)*r;
    const size_t o = (size_t)row*256 + lane + 64*j;
    if (out) out[o] = y;
    if (oh) { const unsigned short h = f2bf(y); oh[o] = h; ol[o] = f2bf(y - bf2f(h)); }
  }
}

// unsort both paths + residual + LN (in-place on X, optional planes)
__global__ __launch_bounds__(256) void ln_unsort_kernel(
    const float* __restrict__ OUTL, const int* __restrict__ INV,
    float* __restrict__ X,
    unsigned short* __restrict__ oh, unsigned short* __restrict__ ol)
{
  const int wave = threadIdx.x >> 6, lane = threadIdx.x & 63;
  const int q = blockIdx.x*4 + wave;
  const int i0 = INV[q], i1 = INV[2048 + q];
  float v[4];
#pragma unroll
  for (int j = 0; j < 4; ++j) {
    int d = lane + 64*j;
    v[j] = X[(size_t)q*256 + d]
         + 0.5f*(OUTL[(size_t)i0*256 + d] + OUTL[(size_t)(2048+i1)*256 + d]);
  }
  float s = v[0]+v[1]+v[2]+v[3];
  for (int off = 32; off; off >>= 1) s += __shfl_xor(s, off);
  float m = s * (1.0f/256.0f);
  float t = 0.f;
#pragma unroll
  for (int j = 0; j < 4; ++j) { float d = v[j]-m; t += d*d; }
  for (int off = 32; off; off >>= 1) t += __shfl_xor(t, off);
  float r = rsqrtf(t * (1.0f/256.0f) + 1e-5f);
#pragma unroll
  for (int j = 0; j < 4; ++j) {
    const float y = (v[j]-m)*r;
    const size_t o = (size_t)q*256 + lane + 64*j;
    X[o] = y;
    if (oh) { const unsigned short h = f2bf(y); oh[o] = h; ol[o] = f2bf(y - bf2f(h)); }
  }
}

// -------------------------- causal depthwise conv (KC=4) + SiLU ------------
__global__ void conv_kernel(const float* __restrict__ PROJ,
    const float* __restrict__ Wc, const float* __restrict__ bc,
    float* __restrict__ XBC)
{
  const int c = threadIdx.x;      // 640
  const int bt = blockIdx.x;      // 4096
  const int t = bt & 2047;
  float acc = bc[c];
#pragma unroll
  for (int j = 0; j < 4; ++j) {
    int d = j - 3;
    if (t + d >= 0)
      acc = fmaf(PROJ[(size_t)(bt + d)*1160 + 512 + c], Wc[c*4+j], acc);
  }
  XBC[(size_t)bt*640 + c] = acc / (1.f + expf(-acc));  // silu
}

// -------------------------- dt softplus + dA -------------------------------
__global__ void dta_kernel(const float* __restrict__ PROJ,
    const float* __restrict__ dtb, const float* __restrict__ Alog,
    float* __restrict__ Ddt, float* __restrict__ Dda)
{
  const int i = blockIdx.x*256 + threadIdx.x;   // 32768 = 4096*8
  const int bt = i >> 3, hh = i & 7;
  float x = PROJ[(size_t)bt*1160 + 1152 + hh] + dtb[hh];
  float dt = (x > 20.f) ? x : log1pf(expf(x));
  float A = -expf(Alog[hh]);
  Ddt[hh*4096 + bt] = dt;
  Dda[hh*4096 + bt] = expf(dt * A);
}

// -------------------------- scan pass 1: per-chunk S_c, P_c ----------------
__global__ __launch_bounds__(64) void scan1_kernel(
    const float* __restrict__ XBC, const float* __restrict__ Ddt,
    const float* __restrict__ Dda, float* __restrict__ SCH, float* __restrict__ PC)
{
  const int blk = blockIdx.x;
  const int c = blk & 31, hh = (blk >> 5) & 7, b = blk >> 8;
  const int lane = threadIdx.x;
  const int t0 = (b << 11) + (c << 6);
  __shared__ float Bsh[64][64];
  __shared__ float Xsh[64][64];
  __shared__ float dAs[64], dts[64];
#pragma unroll
  for (int it = 0; it < 16; ++it) {
    int idx = it*64 + lane;
    int t = idx >> 4, c4 = (idx & 15) << 2;
    *(float4*)&Bsh[t][c4] = *(const float4*)&XBC[(size_t)(t0 + t)*640 + 512 + c4];
    *(float4*)&Xsh[t][c4] = *(const float4*)&XBC[(size_t)(t0 + t)*640 + (hh<<6) + c4];
  }
  dAs[lane] = Dda[hh*4096 + t0 + lane];
  dts[lane] = Ddt[hh*4096 + t0 + lane];
  __syncthreads();
  float h[64];
#pragma unroll
  for (int s = 0; s < 64; ++s) h[s] = 0.f;
  float p = 1.f;
  for (int t = 0; t < 64; ++t) {
    const float dA = dAs[t];
    const float u = dts[t]*Xsh[t][lane];
    p *= dA;
    const float4* B4 = (const float4*)&Bsh[t][0];
#pragma unroll
    for (int s4 = 0; s4 < 16; ++s4) {
      float4 bv = B4[s4];
      h[4*s4+0] = fmaf(h[4*s4+0], dA, bv.x*u);
      h[4*s4+1] = fmaf(h[4*s4+1], dA, bv.y*u);
      h[4*s4+2] = fmaf(h[4*s4+2], dA, bv.z*u);
      h[4*s4+3] = fmaf(h[4*s4+3], dA, bv.w*u);
    }
  }
  float* op = SCH + (size_t)blk*4096 + lane*64;
#pragma unroll
  for (int s4 = 0; s4 < 16; ++s4)
    ((float4*)op)[s4] = make_float4(h[4*s4], h[4*s4+1], h[4*s4+2], h[4*s4+3]);
  if (lane == 0) PC[blk] = p;
}

// -------------------------- sequential cross-chunk combine (in-place) ------
__global__ void combine_kernel(float* __restrict__ SCH, const float* __restrict__ PC)
{
  const int tid = blockIdx.x*256 + threadIdx.x;   // 65536
  const int bh = tid >> 12, ds = tid & 4095;
  float h = 0.f;
  for (int cc = 0; cc < 32; ++cc) {
    size_t o = ((size_t)(bh*32 + cc) << 12) + ds;
    float s = SCH[o];
    SCH[o] = h;
    h = fmaf(h, PC[bh*32+cc], s);
  }
}

// -------------------------- scan pass 2: exact recurrence + y --------------
__global__ __launch_bounds__(64) void scan2_kernel(
    const float* __restrict__ XBC, const float* __restrict__ Ddt,
    const float* __restrict__ Dda, const float* __restrict__ HST,
    const float* __restrict__ Dm, float* __restrict__ Yout)
{
  const int blk = blockIdx.x;
  const int c = blk & 31, hh = (blk >> 5) & 7, b = blk >> 8;
  const int lane = threadIdx.x;
  const int t0 = (b << 11) + (c << 6);
  __shared__ float Bsh[64][64];
  __shared__ float Csh[64][64];
  __shared__ float Xsh[64][64];
  __shared__ float dAs[64], dts[64];
#pragma unroll
  for (int it = 0; it < 16; ++it) {
    int idx = it*64 + lane;
    int t = idx >> 4, c4 = (idx & 15) << 2;
    *(float4*)&Bsh[t][c4] = *(const float4*)&XBC[(size_t)(t0 + t)*640 + 512 + c4];
    *(float4*)&Csh[t][c4] = *(const float4*)&XBC[(size_t)(t0 + t)*640 + 576 + c4];
    *(float4*)&Xsh[t][c4] = *(const float4*)&XBC[(size_t)(t0 + t)*640 + (hh<<6) + c4];
  }
  dAs[lane] = Dda[hh*4096 + t0 + lane];
  dts[lane] = Ddt[hh*4096 + t0 + lane];
  const float Dh = Dm[hh];
  float h[64];
  const float4* hp = (const float4*)(HST + (size_t)blk*4096 + lane*64);
#pragma unroll
  for (int s4 = 0; s4 < 16; ++s4) {
    float4 t4 = hp[s4];
    h[4*s4+0]=t4.x; h[4*s4+1]=t4.y; h[4*s4+2]=t4.z; h[4*s4+3]=t4.w;
  }
  __syncthreads();
  for (int t = 0; t < 64; ++t) {
    const float dA = dAs[t];
    const float u = dts[t]*Xsh[t][lane];
    float y = 0.f;
    const float4* B4 = (const float4*)&Bsh[t][0];
    const float4* C4 = (const float4*)&Csh[t][0];
#pragma unroll
    for (int s4 = 0; s4 < 16; ++s4) {
      float4 bv = B4[s4];
      float4 cv = C4[s4];
      h[4*s4+0] = fmaf(h[4*s4+0], dA, bv.x*u); y = fmaf(cv.x, h[4*s4+0], y);
      h[4*s4+1] = fmaf(h[4*s4+1], dA, bv.y*u); y = fmaf(cv.y, h[4*s4+1], y);
      h[4*s4+2] = fmaf(h[4*s4+2], dA, bv.z*u); y = fmaf(cv.z, h[4*s4+2], y);
      h[4*s4+3] = fmaf(h[4*s4+3], dA, bv.w*u); y = fmaf(cv.w, h[4*s4+3], y);
    }
    Yout[(size_t)(t0 + t)*512 + (hh<<6) + lane] = y + Dh*Xsh[t][lane];
  }
}

// -------------- gate (silu(z)) + RMSNorm over 512 → Yb bf16 planes ---------
__global__ __launch_bounds__(256) void gaterms_kernel(
    const float* __restrict__ Y, const float* __restrict__ PROJ,
    const float* __restrict__ rmsw,
    unsigned short* __restrict__ Oh, unsigned short* __restrict__ Ol)
{
  const int wave = threadIdx.x >> 6, lane = threadIdx.x & 63;
  const int row = blockIdx.x*4 + wave;   // 4096
  float v[8]; float ss = 0.f;
#pragma unroll
  for (int j = 0; j < 8; ++j) {
    float y = Y[(size_t)row*512 + lane + 64*j];
    float z = PROJ[(size_t)row*1160 + lane + 64*j];
    float g = y * (z / (1.f + expf(-z)));
    v[j] = g; ss += g*g;
  }
  for (int off = 32; off; off >>= 1) ss += __shfl_xor(ss, off);
  float r = rsqrtf(ss * (1.0f/512.0f) + 1e-5f);
#pragma unroll
  for (int j = 0; j < 8; ++j) {
    const float o = v[j] * r * rmsw[lane + 64*j];
    const unsigned short h = f2bf(o);
    const size_t ix = (size_t)row*512 + lane + 64*j;
    Oh[ix] = h; Ol[ix] = f2bf(o - bf2f(h));
  }
}

// ---------------------------------------------------------------------------
extern "C" void kernel_launch(void* const* d_in, const int* in_sizes, int n_in,
                              void* d_out, int out_size, void* d_ws, size_t ws_size,
                              hipStream_t stream)
{
  (void)in_sizes; (void)n_in; (void)out_size; (void)ws_size;
  const float* query = (const float*)d_in[0];
  const float* qpos  = (const float*)d_in[1];
  const float* feats = (const float*)d_in[2];
  const float* spos  = (const float*)d_in[3];
  const float* w_q   = (const float*)d_in[4];
  const float* w_v   = (const float*)d_in[5];
  const float* w_o   = (const float*)d_in[6];
  const float* w_k   = (const float*)d_in[7];
  const float* w_b   = (const float*)d_in[8];
  const float* Win   = (const float*)d_in[9];
  const float* Wconv = (const float*)d_in[10];
  const float* bconv = (const float*)d_in[11];
  const float* Alog  = (const float*)d_in[12];
  const float* Dm    = (const float*)d_in[13];
  const float* dtb   = (const float*)d_in[14];
  const float* rmsw  = (const float*)d_in[15];
  const float* Wout  = (const float*)d_in[16];
  const float* fw1   = (const float*)d_in[17];
  const float* fb1   = (const float*)d_in[18];
  const float* fw2   = (const float*)d_in[19];
  const float* fb2   = (const float*)d_in[20];
  const int*   order = (const int*)d_in[21];
  float* out = (float*)d_out;

  char* ws = (char*)d_ws;
  size_t off = 0;
  auto alloc = [&](size_t bytes) -> void* {
    void* p = ws + off;
    off = (off + bytes + 255) & ~(size_t)255;
    return p;
  };
  int*   IDX = (int*)alloc((size_t)2048*8*4);
  int*   INV = (int*)alloc((size_t)4096*4);
  float* PC  = (float*)alloc((size_t)512*4);
  float4* P4 = (float4*)alloc((size_t)32768*16);
  float* Ddt = (float*)alloc((size_t)4096*8*4);
  float* Dda = (float*)alloc((size_t)4096*8*4);
  float* QP  = (float*)alloc((size_t)2048*256*4);
  float* WO  = (float*)alloc((size_t)2048*256*4);
  float* X   = (float*)alloc((size_t)2048*256*4);
  float* U1  = (float*)alloc((size_t)4096*1160*4);  // V (16MB) | PROJ (19MB)
  float* U2  = (float*)alloc((size_t)4096*640*4);   // XBC
  float* SCH = (float*)alloc((size_t)512*4096*4);   // chunk states
  float* Yb  = (float*)alloc((size_t)4096*512*4);
  float* U6  = (float*)alloc((size_t)4096*256*4);   // OUTL | FFO
  // bf16 split planes
  unsigned short* Qh  = (unsigned short*)alloc((size_t)2048*256*2);
  unsigned short* Ql  = (unsigned short*)alloc((size_t)2048*256*2);
  unsigned short* U7h = (unsigned short*)alloc((size_t)32768*256*2); // feats | FFH planes
  unsigned short* U7l = (unsigned short*)alloc((size_t)32768*256*2);
  unsigned short* WBh = (unsigned short*)alloc((size_t)2048*256*2);
  unsigned short* WBl = (unsigned short*)alloc((size_t)2048*256*2);
  unsigned short* XNh = (unsigned short*)alloc((size_t)2048*256*2);
  unsigned short* XNl = (unsigned short*)alloc((size_t)2048*256*2);
  unsigned short* Ybh = (unsigned short*)alloc((size_t)4096*512*2);
  unsigned short* Ybl = (unsigned short*)alloc((size_t)4096*512*2);
  unsigned short* Xh  = (unsigned short*)alloc((size_t)2048*256*2);
  unsigned short* Xl  = (unsigned short*)alloc((size_t)2048*256*2);
  unsigned short* Wqh = (unsigned short*)alloc((size_t)256*256*2);
  unsigned short* Wql = (unsigned short*)alloc((size_t)256*256*2);
  unsigned short* Wvh = (unsigned short*)alloc((size_t)256*256*2);
  unsigned short* Wvl = (unsigned short*)alloc((size_t)256*256*2);
  unsigned short* Woh = (unsigned short*)alloc((size_t)256*256*2);
  unsigned short* Wol = (unsigned short*)alloc((size_t)256*256*2);
  unsigned short* Wih = (unsigned short*)alloc((size_t)2*1160*256*2);
  unsigned short* Wil = (unsigned short*)alloc((size_t)2*1160*256*2);
  unsigned short* Wuh = (unsigned short*)alloc((size_t)2*256*512*2);
  unsigned short* Wul = (unsigned short*)alloc((size_t)2*256*512*2);
  unsigned short* F1h = (unsigned short*)alloc((size_t)1024*256*2);
  unsigned short* F1l = (unsigned short*)alloc((size_t)1024*256*2);
  unsigned short* F2h = (unsigned short*)alloc((size_t)256*1024*2);
  unsigned short* F2l = (unsigned short*)alloc((size_t)256*1024*2);
  float* Vb   = U1;  float* PROJ = U1;
  float* XBC  = U2;
  float* OUTL = U6;  float* FFO  = U6;
  unsigned short* FFHh = U7h;  // feats planes dead after stage 1
  unsigned short* FFHl = U7l;

  auto cvt = [&](const float* s, unsigned short* h, unsigned short* l, int n) {
    cvt_kernel<<<(n/4 + 255)/256, 256, 0, stream>>>(s, h, l, n/4);
  };

  // --- stage 1: KNN + aggregation ---
  inv_kernel<<<16, 256, 0, stream>>>(order, INV);
  prep_kernel<<<128, 256, 0, stream>>>(spos, P4);
  knn_kernel<<<512, 256, 0, stream>>>(qpos, P4, IDX);
  cvt(query, Qh, Ql, 2048*256);
  cvt(feats, U7h, U7l, 32768*256);
  cvt(w_q, Wqh, Wql, 256*256);
  cvt(w_v, Wvh, Wvl, 256*256);
  cvt(w_o, Woh, Wol, 256*256);
  cvt(Win, Wih, Wil, 2*1160*256);
  cvt(Wout, Wuh, Wul, 2*256*512);
  cvt(fw1, F1h, F1l, 1024*256);
  cvt(fw2, F2h, F2l, 256*1024);
  gemm_mfma<<<dim3(16,4), 256, 0, stream>>>(Qh, Ql, nullptr, Wqh, Wql, nullptr,
                                            QP, nullptr, nullptr, 2048,256,256,0);
  gemm_mfma<<<dim3(128,4), 256, 0, stream>>>(U7h, U7l, IDX, Wvh, Wvl, nullptr,
                                             Vb, nullptr, nullptr, 16384,256,256,0);
  kwmix_kernel<<<512, 256, 0, stream>>>(QP, w_k, w_b, Vb, WBh, WBl);
  gemm_mfma<<<dim3(16,4), 256, 0, stream>>>(WBh, WBl, nullptr, Woh, Wol, nullptr,
                                            WO, nullptr, nullptr, 2048,256,256,0);
  ln_kernel<<<512, 256, 0, stream>>>(WO, query, X, nullptr, nullptr, 2048);

  // --- stage 2: two Mamba2 layers ---
  for (int l = 0; l < 2; ++l) {
    ln_kernel<<<512, 256, 0, stream>>>(X, nullptr, nullptr, XNh, XNl, 2048);
    gemm_mfma<<<dim3(32,19), 256, 0, stream>>>(XNh, XNl, order,
                                               Wih + (size_t)l*1160*256,
                                               Wil + (size_t)l*1160*256,
                                               nullptr, PROJ, nullptr, nullptr,
                                               4096,1160,256,0);
    conv_kernel<<<4096, 640, 0, stream>>>(PROJ, Wconv + l*640*4, bconv + l*640, XBC);
    dta_kernel<<<128, 256, 0, stream>>>(PROJ, dtb + l*8, Alog + l*8, Ddt, Dda);
    scan1_kernel<<<512, 64, 0, stream>>>(XBC, Ddt, Dda, SCH, PC);
    combine_kernel<<<256, 256, 0, stream>>>(SCH, PC);
    scan2_kernel<<<512, 64, 0, stream>>>(XBC, Ddt, Dda, SCH, Dm + l*8, Yb);
    gaterms_kernel<<<1024, 256, 0, stream>>>(Yb, PROJ, rmsw + l*512, Ybh, Ybl);
    gemm_mfma<<<dim3(32,4), 256, 0, stream>>>(Ybh, Ybl, nullptr,
                                              Wuh + (size_t)l*256*512,
                                              Wul + (size_t)l*256*512,
                                              nullptr, OUTL, nullptr, nullptr,
                                              4096,256,512,0);
    ln_unsort_kernel<<<512, 256, 0, stream>>>(OUTL, INV, X,
                                              (l==1) ? Xh : nullptr,
                                              (l==1) ? Xl : nullptr);
  }

  // --- stage 3: FFN ---
  gemm_mfma<<<dim3(16,16), 256, 0, stream>>>(Xh, Xl, nullptr, F1h, F1l, fb1,
                                             nullptr, FFHh, FFHl, 2048,1024,256,1);
  gemm_mfma<<<dim3(16,4), 256, 0, stream>>>(FFHh, FFHl, nullptr, F2h, F2l, fb2,
                                            FFO, nullptr, nullptr, 2048,256,1024,0);
  ln_kernel<<<512, 256, 0, stream>>>(FFO, X, out, nullptr, nullptr, 2048);
}